// Round 15
// baseline (112.598 us; speedup 1.0000x reference)
//
#include <hip/hip_runtime.h>
#include <math.h>

#define FF 256
#define CC 100000
#define PMARG 0.2f
#define NMARG 0.3f
#define NCT 6250                 // col-tiles of 16 (6250*16 == CC exactly)
#define RPB 12500                // repack blocks (256 frags each)
#define NGB3 1563                // gemm blocks: 4 waves x 1 ct
#define NPART (NGB3 * 4)         // 6252 per-wave partial slots
#define W_A 0                    // ws floats: A-pack bf16 frags (32KB)
#define W_GRAM 8192              // Gram 64x64 f32
#define W_SE 12288               // 64 row exp-sums
#define W_PART 12352             // per-wave exp partials: NPART*64 floats
#define W_VPACK_BYTES 2000000ULL // vpack: NCT*8*64*16 = 51.2MB
#define WS_NEED (W_VPACK_BYTES + (size_t)NCT * 8 * 64 * 16)

typedef __attribute__((ext_vector_type(8))) short short8;   // 8 bf16 = 4 VGPR
typedef __attribute__((ext_vector_type(4))) float f32x4;

__device__ __forceinline__ float wredf(float v) {
#pragma unroll
    for (int s = 1; s < 64; s <<= 1) v += __shfl_xor(v, s, 64);
    return v;
}
__device__ __forceinline__ short f2bf(float f) {
    unsigned u = __float_as_uint(f);
    unsigned r = (u + 0x7fffu + ((u >> 16) & 1u)) >> 16;
    return (short)r;
}
__device__ __forceinline__ short8 pack8(float4 a, float4 b) {
    short8 o;
    o[0] = f2bf(a.x); o[1] = f2bf(a.y); o[2] = f2bf(a.z); o[3] = f2bf(a.w);
    o[4] = f2bf(b.x); o[5] = f2bf(b.y); o[6] = f2bf(b.z); o[7] = f2bf(b.w);
    return o;
}
__device__ __forceinline__ short8 pack8v(f32x4 a, f32x4 b) {
    short8 o;
    o[0] = f2bf(a[0]); o[1] = f2bf(a[1]); o[2] = f2bf(a[2]); o[3] = f2bf(a[3]);
    o[4] = f2bf(b[0]); o[5] = f2bf(b[1]); o[6] = f2bf(b[2]); o[7] = f2bf(b[3]);
    return o;
}
__device__ __forceinline__ float dot4(float4 a, float4 b) {
    return a.x * b.x + a.y * b.y + a.z * b.z + a.w * b.w;
}

// blocks 0..3: Gram quadrants (32x32 each, f32); block 4: A-pack
__global__ __launch_bounds__(256) void k_prep(const float* __restrict__ in,
                                              float* __restrict__ ws) {
    int tid = threadIdx.x;
    int b = blockIdx.x;
    const float4* __restrict__ in4 = (const float4*)in;
    if (b == 4) {
        short8* __restrict__ wsa = (short8*)(ws + W_A);
#pragma unroll
        for (int i = 0; i < 8; ++i) {
            int idx = i * 256 + tid;          // (mt*8+ks)*64 + lane
            int lane = idx & 63;
            int ks = (idx >> 6) & 7;
            int mt = idx >> 9;
            int row = mt * 16 + (lane & 15);
            int kq = ks * 8 + (lane >> 4) * 2;
            wsa[idx] = pack8(in4[row * 64 + kq], in4[row * 64 + kq + 1]);
        }
        return;
    }
    __shared__ float4 sIn[64 * 64];       // 64KB inputs
#pragma unroll
    for (int i = 0; i < 16; ++i) sIn[i * 256 + tid] = in4[i * 256 + tid];
    __syncthreads();
    int qr = b >> 1, qc = b & 1;
    int r0 = qr * 32 + (tid >> 4) * 2;
    int c0 = qc * 32 + (tid & 15) * 2;
    float g00 = 0.f, g01 = 0.f, g10 = 0.f, g11 = 0.f;
    for (int kq = 0; kq < 64; ++kq) {
        float4 a0 = sIn[(r0 + 0) * 64 + kq];
        float4 a1 = sIn[(r0 + 1) * 64 + kq];
        float4 b0 = sIn[(c0 + 0) * 64 + kq];
        float4 b1 = sIn[(c0 + 1) * 64 + kq];
        g00 += dot4(a0, b0); g01 += dot4(a0, b1);
        g10 += dot4(a1, b0); g11 += dot4(a1, b1);
    }
    float* G = ws + W_GRAM;
    G[(r0 + 0) * 64 + c0 + 0] = g00;
    G[(r0 + 0) * 64 + c0 + 1] = g01;
    G[(r0 + 1) * 64 + c0 + 0] = g10;
    G[(r0 + 1) * 64 + c0 + 1] = g11;
}

// Pure streaming repack: ONE fragment per thread, no LDS, no barrier, no
// dependency chains (fillBuffer-class shape, ~97 waves/CU of TLP).
// Read: 32B contiguous per thread (per instr: 16 rows x 128B full lines).
// Write: 16B per thread, perfectly coalesced (1KB per instruction).
__global__ __launch_bounds__(256) void k_repack(const float* __restrict__ V,
                                                float* __restrict__ ws) {
    int idx = blockIdx.x * 256 + threadIdx.x;   // 0 .. NCT*512-1
    int ct = idx >> 9;
    int rem = idx & 511;
    int ks = rem >> 6;
    int l = rem & 63;
    int row = ct * 16 + (l & 15);
    int kq = ks * 8 + (l >> 4) * 2;             // float4 index in the row
    const float4* __restrict__ src = (const float4*)V + (size_t)row * 64 + kq;
    float4 x = src[0];
    float4 y = src[1];
    short8* __restrict__ vp = (short8*)((char*)ws + W_VPACK_BYTES);
    vp[idx] = pack8(x, y);
}

// GEMM from vpack (R10's proven-fast consumption): wave = 1 distinct ct
// (16 cols x all 64 rows), 8 coalesced 16B B-loads prefetched, 32 MFMA.
// No LDS, no __syncthreads; per-wave partials straight to ws.
__global__ __launch_bounds__(256, 2) void k_gemm3v(const float* __restrict__ ws_in,
                                                   float* __restrict__ logits,
                                                   float* __restrict__ ws) {
    int tid = threadIdx.x;
    int lane = tid & 63, w = tid >> 6;
    int ct = blockIdx.x * 4 + w;                // 0..6251 (last block partial)
    int g = lane >> 4, c4 = lane & 15;
    bool ctv = ct < NCT;
    int cts = ctv ? ct : 0;

    const short8* __restrict__ vp =
        (const short8*)((const char*)ws_in + W_VPACK_BYTES) + (size_t)cts * 512 + lane;
    short8 bfr[8];
#pragma unroll
    for (int ks = 0; ks < 8; ++ks) bfr[ks] = vp[ks * 64];   // coalesced bf16

    const short8* __restrict__ ap = (const short8*)(ws_in + W_A) + lane;
    f32x4 acc[4];
#pragma unroll
    for (int mt = 0; mt < 4; ++mt) acc[mt] = (f32x4){0.f, 0.f, 0.f, 0.f};
#pragma unroll
    for (int ks = 0; ks < 8; ++ks)
#pragma unroll
        for (int mt = 0; mt < 4; ++mt) {
            short8 a = ap[(mt * 8 + ks) * 64];   // L1-hot, coalesced
            acc[mt] = __builtin_amdgcn_mfma_f32_16x16x32_bf16(a, bfr[ks],
                                                              acc[mt], 0, 0, 0);
        }

    // ---- epilogue: stores + per-wave exp partials, zero LDS/barriers ----
    int col = ct * 16 + c4;
    float* __restrict__ P = ws + W_PART + (size_t)(blockIdx.x * 4 + w) * 64;
#pragma unroll
    for (int mt = 0; mt < 4; ++mt)
#pragma unroll
        for (int r = 0; r < 4; ++r) {
            int row = mt * 16 + g * 4 + r;
            float lg = acc[mt][r];
            if (ctv) logits[(size_t)row * CC + col] = lg;
            float e = ctv ? expf(lg) : 0.f;      // |logit| <= ~19, safe
            e += __shfl_xor(e, 1, 64); e += __shfl_xor(e, 2, 64);
            e += __shfl_xor(e, 4, 64); e += __shfl_xor(e, 8, 64);
            if (c4 == 0) P[row] = e;             // deterministic
        }
}

// Fallback (R14): raw-V streaming gemm, used if ws too small for vpack
__global__ __launch_bounds__(256, 2) void k_gemm3(const float* __restrict__ V,
                                                  const float* __restrict__ ws_in,
                                                  float* __restrict__ logits,
                                                  float* __restrict__ ws) {
    int tid = threadIdx.x;
    int lane = tid & 63, w = tid >> 6;
    int ct = blockIdx.x * 4 + w;
    int g = lane >> 4, c4 = lane & 15;
    bool ctv = ct < NCT;
    int vr = ctv ? (ct * 16 + c4) : (CC - 1);
    const f32x4* __restrict__ vp = (const f32x4*)V + (size_t)vr * 64 + g * 2;
    f32x4 bv[8][2];
#pragma unroll
    for (int ks = 0; ks < 8; ++ks) {
        bv[ks][0] = vp[ks * 8];
        bv[ks][1] = vp[ks * 8 + 1];
    }
    const short8* __restrict__ ap = (const short8*)(ws_in + W_A) + lane;
    f32x4 acc[4];
#pragma unroll
    for (int mt = 0; mt < 4; ++mt) acc[mt] = (f32x4){0.f, 0.f, 0.f, 0.f};
#pragma unroll
    for (int ks = 0; ks < 8; ++ks) {
        short8 bf = pack8v(bv[ks][0], bv[ks][1]);
#pragma unroll
        for (int mt = 0; mt < 4; ++mt) {
            short8 a = ap[(mt * 8 + ks) * 64];
            acc[mt] = __builtin_amdgcn_mfma_f32_16x16x32_bf16(a, bf, acc[mt], 0, 0, 0);
        }
    }
    int col = ct * 16 + c4;
    float* __restrict__ P = ws + W_PART + (size_t)(blockIdx.x * 4 + w) * 64;
#pragma unroll
    for (int mt = 0; mt < 4; ++mt)
#pragma unroll
        for (int r = 0; r < 4; ++r) {
            int row = mt * 16 + g * 4 + r;
            float lg = acc[mt][r];
            if (ctv) logits[(size_t)row * CC + col] = lg;
            float e = ctv ? expf(lg) : 0.f;
            e += __shfl_xor(e, 1, 64); e += __shfl_xor(e, 2, 64);
            e += __shfl_xor(e, 4, 64); e += __shfl_xor(e, 8, 64);
            if (c4 == 0) P[row] = e;
        }
}

// 64 blocks (one per batch row): deterministic reduce of exp partials
__global__ __launch_bounds__(256) void k_comb(const float* __restrict__ ws_in,
                                              float* __restrict__ ws) {
    __shared__ float sS[256];
    int row = blockIdx.x;
    int tid = threadIdx.x;
    const float* __restrict__ P = ws_in + W_PART;
    float s = 0.f;
    for (int b = tid; b < NPART; b += 256) s += P[(size_t)b * 64 + row];
    sS[tid] = s;
    __syncthreads();
    if (tid < 128) sS[tid] += sS[tid + 128];
    __syncthreads();
    if (tid < 64) {
        float v = sS[tid] + sS[tid + 64];
        v = wredf(v);
        if (tid == 0) ws[W_SE + row] = v;
    }
}

__device__ __forceinline__ bool mask_at(const void* p, int idx, int mode) {
    if (mode == 0) return ((const int*)p)[idx] != 0;
    if (mode == 1) return ((const float*)p)[idx] != 0.f;
    return ((const unsigned char*)p)[idx] != 0;
}

// 1 block x 256 threads: stage G + masks into LDS, wave 0 runs the tail
__global__ __launch_bounds__(256) void k_final(const int* __restrict__ targets,
                                               const void* __restrict__ pmask,
                                               const void* __restrict__ nmask,
                                               const float* __restrict__ logits,
                                               const float* __restrict__ ws,
                                               float* __restrict__ out) {
    __shared__ float sG[4096];
    __shared__ char sPM[16384];
    __shared__ char sNM[16384];
    __shared__ int sMode;
    int tid = threadIdx.x;

    float myLogit = 0.f, mySe = 0.f;
    if (tid < 64) {
        int tgt = targets[tid];
        myLogit = logits[(size_t)tid * CC + tgt];
        mySe = ws[W_SE + tid];
    }
    {
        const float4* __restrict__ G4 = (const float4*)(ws + W_GRAM);
        float4* sG4 = (float4*)sG;
#pragma unroll
        for (int i = 0; i < 4; ++i) sG4[tid + i * 256] = G4[tid + i * 256];
    }
    if (tid < 64) {
        const unsigned int* pw = (const unsigned int*)pmask;
        int okInt = 1, okFlt = 1;
#pragma unroll
        for (int i = 0; i < 16; ++i) {
            unsigned int wv = pw[tid * 16 + i];
            okInt = okInt && (wv <= 1u);
            okFlt = okFlt && (wv == 0u || wv == 0x3f800000u);
        }
        int mode = __all(okInt) ? 0 : (__all(okFlt) ? 1 : 2);
        if (tid == 0) sMode = mode;
    }
    __syncthreads();
    int mode = sMode;
    int mq = (mode == 2) ? 256 : 1024;
    for (int i = tid; i < mq; i += 256) {
        ((float4*)sPM)[i] = ((const float4*)pmask)[i];
        ((float4*)sNM)[i] = ((const float4*)nmask)[i];
    }
    __syncthreads();
    if (tid >= 64) return;

    int lane = tid;
    float lse = logf(mySe);
    float nll = lse - myLogit;

    float rinv = rsqrtf(sG[lane * 64 + lane]);

    float minp = INFINITY, maxthd = -INFINITY;
    for (int j = 0; j < 64; ++j) {
        float rj = __shfl(rinv, j, 64);
        float sim = sG[lane * 64 + j] * rinv * rj;
        sim = fminf(1.f, fmaxf(-1.f, sim));
        if (j != lane) {
            bool pm = mask_at(sPM, lane * 64 + j, mode);
            float ps = pm ? sim : 2.0f;
            minp = fminf(minp, ps);
            maxthd = fmaxf(maxthd, pm ? sim : -2.0f);   // sentinel 2.0 -> -2.0
        }
    }
    float n_thrd = minp - NMARG;
    float p_thrd = maxthd - PMARG;

    float hps = 0.f, hns = 0.f, hpc = 0.f, hnc = 0.f;
    for (int j = 0; j < 64; ++j) {
        float rj = __shfl(rinv, j, 64);
        float sim = sG[lane * 64 + j] * rinv * rj;
        sim = fminf(1.f, fmaxf(-1.f, sim));
        if (j != lane) {
            bool pm = mask_at(sPM, lane * 64 + j, mode);
            bool nm = mask_at(sNM, lane * 64 + j, mode);
            float ps = pm ? sim : 2.0f;
            float ns = nm ? sim : 2.0f;
            if (ps < p_thrd) { hps += log1pf(expf(-ps)); hpc += 1.f; }
            if (ns < n_thrd) { hns += log1pf(expf(-ns)); hnc += 1.f; }
        }
    }

    float snll = wredf(nll);
    float shps = wredf(hps);
    float shns = wredf(hns);
    float shpc = wredf(hpc);
    float shnc = wredf(hnc);
    if (lane == 0) {
        float bu = snll * (1.f / 64.f);
        float hp = shpc > 0.f ? shps / shpc : 0.f;
        float hn = shnc > 0.f ? shns / shnc : 0.f;
        out[0] = bu + hp + hn;
    }
}

extern "C" void kernel_launch(void* const* d_in, const int* in_sizes, int n_in,
                              void* d_out, int out_size, void* d_ws, size_t ws_size,
                              hipStream_t stream) {
    const float* inputs = (const float*)d_in[0];
    const int* targets  = (const int*)d_in[1];
    const void* pmask   = d_in[2];
    const void* nmask   = d_in[3];
    const float* V      = (const float*)d_in[4];
    float* out = (float*)d_out;      // out[0] = loss
    float* logits = out + 1;         // out[1..] = logits [64][100000] row-major
    float* ws = (float*)d_ws;        // A-pack | Gram | se | partials | vpack

    hipLaunchKernelGGL(k_prep, dim3(5), dim3(256), 0, stream, inputs, ws);
    if (ws_size >= WS_NEED) {
        hipLaunchKernelGGL(k_repack, dim3(RPB), dim3(256), 0, stream, V, ws);
        hipLaunchKernelGGL(k_gemm3v, dim3(NGB3), dim3(256), 0, stream,
                           ws, logits, ws);
    } else {
        hipLaunchKernelGGL(k_gemm3, dim3(NGB3), dim3(256), 0, stream,
                           V, ws, logits, ws);
    }
    hipLaunchKernelGGL(k_comb, dim3(64), dim3(256), 0, stream, ws, ws);
    hipLaunchKernelGGL(k_final, dim3(1), dim3(256), 0, stream,
                       targets, pmask, nmask, logits, ws, out);
}

// Round 16
// 99.234 us; speedup vs baseline: 1.1347x; 1.1347x over previous
//
#include <hip/hip_runtime.h>
#include <math.h>

#define FF 256
#define CC 100000
#define PMARG 0.2f
#define NMARG 0.3f
#define NCT 6250                 // col-tiles of 16 (6250*16 == CC exactly)
#define NGB 1563                 // gemm blocks: 4 waves x 1 ct
#define NPART (NGB * 4)          // per-wave partial slots
#define W_A 0                    // ws floats: A-pack bf16 frags (32KB)
#define W_GRAM 8192              // Gram 64x64 f32
#define W_SE 12288               // 64 row exp-sums
#define W_PART 12352             // per-wave exp partials: NPART*64 floats

typedef __attribute__((ext_vector_type(8))) short short8;   // 8 bf16 = 4 VGPR
typedef __attribute__((ext_vector_type(4))) float f32x4;

__device__ __forceinline__ float wredf(float v) {
#pragma unroll
    for (int s = 1; s < 64; s <<= 1) v += __shfl_xor(v, s, 64);
    return v;
}
__device__ __forceinline__ short f2bf(float f) {
    unsigned u = __float_as_uint(f);
    unsigned r = (u + 0x7fffu + ((u >> 16) & 1u)) >> 16;
    return (short)r;
}
__device__ __forceinline__ short8 pack8(float4 a, float4 b) {
    short8 o;
    o[0] = f2bf(a.x); o[1] = f2bf(a.y); o[2] = f2bf(a.z); o[3] = f2bf(a.w);
    o[4] = f2bf(b.x); o[5] = f2bf(b.y); o[6] = f2bf(b.z); o[7] = f2bf(b.w);
    return o;
}
__device__ __forceinline__ short8 pack8v(f32x4 a, f32x4 b) {
    short8 o;
    o[0] = f2bf(a[0]); o[1] = f2bf(a[1]); o[2] = f2bf(a[2]); o[3] = f2bf(a[3]);
    o[4] = f2bf(b[0]); o[5] = f2bf(b[1]); o[6] = f2bf(b[2]); o[7] = f2bf(b[3]);
    return o;
}
__device__ __forceinline__ float dot4(float4 a, float4 b) {
    return a.x * b.x + a.y * b.y + a.z * b.z + a.w * b.w;
}

// blocks 0..3: Gram quadrants (32x32 each, f32); block 4: A-pack
__global__ __launch_bounds__(256) void k_prep(const float* __restrict__ in,
                                              float* __restrict__ ws) {
    int tid = threadIdx.x;
    int b = blockIdx.x;
    const float4* __restrict__ in4 = (const float4*)in;
    if (b == 4) {
        short8* __restrict__ wsa = (short8*)(ws + W_A);
#pragma unroll
        for (int i = 0; i < 8; ++i) {
            int idx = i * 256 + tid;          // (mt*8+ks)*64 + lane
            int lane = idx & 63;
            int ks = (idx >> 6) & 7;
            int mt = idx >> 9;
            int row = mt * 16 + (lane & 15);
            int kq = ks * 8 + (lane >> 4) * 2;
            wsa[idx] = pack8(in4[row * 64 + kq], in4[row * 64 + kq + 1]);
        }
        return;
    }
    __shared__ float4 sIn[64 * 64];       // 64KB inputs
#pragma unroll
    for (int i = 0; i < 16; ++i) sIn[i * 256 + tid] = in4[i * 256 + tid];
    __syncthreads();
    int qr = b >> 1, qc = b & 1;
    int r0 = qr * 32 + (tid >> 4) * 2;
    int c0 = qc * 32 + (tid & 15) * 2;
    float g00 = 0.f, g01 = 0.f, g10 = 0.f, g11 = 0.f;
    for (int kq = 0; kq < 64; ++kq) {
        float4 a0 = sIn[(r0 + 0) * 64 + kq];
        float4 a1 = sIn[(r0 + 1) * 64 + kq];
        float4 b0 = sIn[(c0 + 0) * 64 + kq];
        float4 b1 = sIn[(c0 + 1) * 64 + kq];
        g00 += dot4(a0, b0); g01 += dot4(a0, b1);
        g10 += dot4(a1, b0); g11 += dot4(a1, b1);
    }
    float* G = ws + W_GRAM;
    G[(r0 + 0) * 64 + c0 + 0] = g00;
    G[(r0 + 0) * 64 + c0 + 1] = g01;
    G[(r0 + 1) * 64 + c0 + 0] = g10;
    G[(r0 + 1) * 64 + c0 + 1] = g11;
}

// Streaming GEMM with FORCED up-front B loads: 16 inline-asm
// global_load_dwordx4 (volatile asm cannot be sunk/split -> one latency
// exposure per wave, not 8). A-pack staged to LDS (removes ~200MB of L2
// re-reads; conflict-free lane-consecutive ds_read_b128). Wave = 1 distinct
// ct (16 cols) x all 64 rows; per-wave exp partials; one staging barrier.
__global__ __launch_bounds__(256, 3) void k_gemm4(const float* __restrict__ V,
                                                  const float* __restrict__ ws_in,
                                                  float* __restrict__ logits,
                                                  float* __restrict__ ws) {
    __shared__ short8 sA[2048];           // 32KB A-pack copy
    int tid = threadIdx.x;
    int lane = tid & 63, w = tid >> 6;
    int ct = blockIdx.x * 4 + w;          // 0..6251 (tail waves clamped)
    int g = lane >> 4, c4 = lane & 15;
    bool ctv = ct < NCT;
    int vr = ctv ? (ct * 16 + c4) : (CC - 1);

    // ---- 16 asm B-loads, all in flight together (64 VGPRs forced live) ----
    const f32x4* vp = (const f32x4*)V + (size_t)vr * 64 + g * 2;
    f32x4 b0a, b0b, b1a, b1b, b2a, b2b, b3a, b3b;
    f32x4 b4a, b4b, b5a, b5b, b6a, b6b, b7a, b7b;
#define LDB(reg, off)                                                         \
    asm volatile("global_load_dwordx4 %0, %1, off" : "=v"(reg) : "v"(vp + (off)));
    LDB(b0a, 0)  LDB(b0b, 1)  LDB(b1a, 8)  LDB(b1b, 9)
    LDB(b2a, 16) LDB(b2b, 17) LDB(b3a, 24) LDB(b3b, 25)
    LDB(b4a, 32) LDB(b4b, 33) LDB(b5a, 40) LDB(b5b, 41)
    LDB(b6a, 48) LDB(b6b, 49) LDB(b7a, 56) LDB(b7b, 57)
#undef LDB

    // ---- stage A-pack to LDS while B loads are in flight ----
    const short8* __restrict__ wsa = (const short8*)(ws_in + W_A);
#pragma unroll
    for (int i = 0; i < 8; ++i) sA[i * 256 + tid] = wsa[i * 256 + tid];
    __syncthreads();
    asm volatile("s_waitcnt vmcnt(0)" ::: "memory");   // B regs valid now
    __builtin_amdgcn_sched_barrier(0);                 // rule #18 fence

    const short8* __restrict__ sap = sA + lane;
    f32x4 acc0 = {0.f, 0.f, 0.f, 0.f};
    f32x4 acc1 = {0.f, 0.f, 0.f, 0.f};
    f32x4 acc2 = {0.f, 0.f, 0.f, 0.f};
    f32x4 acc3 = {0.f, 0.f, 0.f, 0.f};
#define GSTEP(K, BA, BB)                                                      \
    {                                                                         \
        short8 bf = pack8v(BA, BB);                                           \
        short8 a0 = sap[(0 * 8 + K) * 64];                                    \
        short8 a1 = sap[(1 * 8 + K) * 64];                                    \
        short8 a2 = sap[(2 * 8 + K) * 64];                                    \
        short8 a3 = sap[(3 * 8 + K) * 64];                                    \
        acc0 = __builtin_amdgcn_mfma_f32_16x16x32_bf16(a0, bf, acc0, 0, 0, 0);\
        acc1 = __builtin_amdgcn_mfma_f32_16x16x32_bf16(a1, bf, acc1, 0, 0, 0);\
        acc2 = __builtin_amdgcn_mfma_f32_16x16x32_bf16(a2, bf, acc2, 0, 0, 0);\
        acc3 = __builtin_amdgcn_mfma_f32_16x16x32_bf16(a3, bf, acc3, 0, 0, 0);\
    }
    GSTEP(0, b0a, b0b)
    GSTEP(1, b1a, b1b)
    GSTEP(2, b2a, b2b)
    GSTEP(3, b3a, b3b)
    GSTEP(4, b4a, b4b)
    GSTEP(5, b5a, b5b)
    GSTEP(6, b6a, b6b)
    GSTEP(7, b7a, b7b)
#undef GSTEP

    // ---- epilogue: stores + per-wave exp partials ----
    int col = ct * 16 + c4;
    float* __restrict__ P = ws + W_PART + (size_t)(blockIdx.x * 4 + w) * 64;
#pragma unroll
    for (int mt = 0; mt < 4; ++mt) {
        f32x4 a = (mt == 0) ? acc0 : (mt == 1) ? acc1 : (mt == 2) ? acc2 : acc3;
#pragma unroll
        for (int r = 0; r < 4; ++r) {
            int row = mt * 16 + g * 4 + r;
            float lg = a[r];
            if (ctv) logits[(size_t)row * CC + col] = lg;
            float e = ctv ? expf(lg) : 0.f;      // |logit| <= ~19, safe
            e += __shfl_xor(e, 1, 64); e += __shfl_xor(e, 2, 64);
            e += __shfl_xor(e, 4, 64); e += __shfl_xor(e, 8, 64);
            if (c4 == 0) P[row] = e;             // deterministic
        }
    }
}

// 64 blocks (one per batch row): deterministic reduce of exp partials
__global__ __launch_bounds__(256) void k_comb(const float* __restrict__ ws_in,
                                              float* __restrict__ ws) {
    __shared__ float sS[256];
    int row = blockIdx.x;
    int tid = threadIdx.x;
    const float* __restrict__ P = ws_in + W_PART;
    float s = 0.f;
    for (int b = tid; b < NPART; b += 256) s += P[(size_t)b * 64 + row];
    sS[tid] = s;
    __syncthreads();
    if (tid < 128) sS[tid] += sS[tid + 128];
    __syncthreads();
    if (tid < 64) {
        float v = sS[tid] + sS[tid + 64];
        v = wredf(v);
        if (tid == 0) ws[W_SE + row] = v;
    }
}

__device__ __forceinline__ bool mask_at(const void* p, int idx, int mode) {
    if (mode == 0) return ((const int*)p)[idx] != 0;
    if (mode == 1) return ((const float*)p)[idx] != 0.f;
    return ((const unsigned char*)p)[idx] != 0;
}

// 1 block x 256 threads: stage G + masks into LDS, wave 0 runs the tail
__global__ __launch_bounds__(256) void k_final(const int* __restrict__ targets,
                                               const void* __restrict__ pmask,
                                               const void* __restrict__ nmask,
                                               const float* __restrict__ logits,
                                               const float* __restrict__ ws,
                                               float* __restrict__ out) {
    __shared__ float sG[4096];
    __shared__ char sPM[16384];
    __shared__ char sNM[16384];
    __shared__ int sMode;
    int tid = threadIdx.x;

    float myLogit = 0.f, mySe = 0.f;
    if (tid < 64) {
        int tgt = targets[tid];
        myLogit = logits[(size_t)tid * CC + tgt];
        mySe = ws[W_SE + tid];
    }
    {
        const float4* __restrict__ G4 = (const float4*)(ws + W_GRAM);
        float4* sG4 = (float4*)sG;
#pragma unroll
        for (int i = 0; i < 4; ++i) sG4[tid + i * 256] = G4[tid + i * 256];
    }
    if (tid < 64) {
        const unsigned int* pw = (const unsigned int*)pmask;
        int okInt = 1, okFlt = 1;
#pragma unroll
        for (int i = 0; i < 16; ++i) {
            unsigned int wv = pw[tid * 16 + i];
            okInt = okInt && (wv <= 1u);
            okFlt = okFlt && (wv == 0u || wv == 0x3f800000u);
        }
        int mode = __all(okInt) ? 0 : (__all(okFlt) ? 1 : 2);
        if (tid == 0) sMode = mode;
    }
    __syncthreads();
    int mode = sMode;
    int mq = (mode == 2) ? 256 : 1024;
    for (int i = tid; i < mq; i += 256) {
        ((float4*)sPM)[i] = ((const float4*)pmask)[i];
        ((float4*)sNM)[i] = ((const float4*)nmask)[i];
    }
    __syncthreads();
    if (tid >= 64) return;

    int lane = tid;
    float lse = logf(mySe);
    float nll = lse - myLogit;

    float rinv = rsqrtf(sG[lane * 64 + lane]);

    float minp = INFINITY, maxthd = -INFINITY;
    for (int j = 0; j < 64; ++j) {
        float rj = __shfl(rinv, j, 64);
        float sim = sG[lane * 64 + j] * rinv * rj;
        sim = fminf(1.f, fmaxf(-1.f, sim));
        if (j != lane) {
            bool pm = mask_at(sPM, lane * 64 + j, mode);
            float ps = pm ? sim : 2.0f;
            minp = fminf(minp, ps);
            maxthd = fmaxf(maxthd, pm ? sim : -2.0f);   // sentinel 2.0 -> -2.0
        }
    }
    float n_thrd = minp - NMARG;
    float p_thrd = maxthd - PMARG;

    float hps = 0.f, hns = 0.f, hpc = 0.f, hnc = 0.f;
    for (int j = 0; j < 64; ++j) {
        float rj = __shfl(rinv, j, 64);
        float sim = sG[lane * 64 + j] * rinv * rj;
        sim = fminf(1.f, fmaxf(-1.f, sim));
        if (j != lane) {
            bool pm = mask_at(sPM, lane * 64 + j, mode);
            bool nm = mask_at(sNM, lane * 64 + j, mode);
            float ps = pm ? sim : 2.0f;
            float ns = nm ? sim : 2.0f;
            if (ps < p_thrd) { hps += log1pf(expf(-ps)); hpc += 1.f; }
            if (ns < n_thrd) { hns += log1pf(expf(-ns)); hnc += 1.f; }
        }
    }

    float snll = wredf(nll);
    float shps = wredf(hps);
    float shns = wredf(hns);
    float shpc = wredf(hpc);
    float shnc = wredf(hnc);
    if (lane == 0) {
        float bu = snll * (1.f / 64.f);
        float hp = shpc > 0.f ? shps / shpc : 0.f;
        float hn = shnc > 0.f ? shns / shnc : 0.f;
        out[0] = bu + hp + hn;
    }
}

extern "C" void kernel_launch(void* const* d_in, const int* in_sizes, int n_in,
                              void* d_out, int out_size, void* d_ws, size_t ws_size,
                              hipStream_t stream) {
    const float* inputs = (const float*)d_in[0];
    const int* targets  = (const int*)d_in[1];
    const void* pmask   = d_in[2];
    const void* nmask   = d_in[3];
    const float* V      = (const float*)d_in[4];
    float* out = (float*)d_out;      // out[0] = loss
    float* logits = out + 1;         // out[1..] = logits [64][100000] row-major
    float* ws = (float*)d_ws;        // A-pack | Gram | se | per-wave partials

    hipLaunchKernelGGL(k_prep, dim3(5), dim3(256), 0, stream, inputs, ws);
    hipLaunchKernelGGL(k_gemm4, dim3(NGB), dim3(256), 0, stream,
                       V, ws, logits, ws);
    hipLaunchKernelGGL(k_comb, dim3(64), dim3(256), 0, stream, ws, ws);
    hipLaunchKernelGGL(k_final, dim3(1), dim3(256), 0, stream,
                       targets, pmask, nmask, logits, ws, out);
}

// Round 17
// 94.810 us; speedup vs baseline: 1.1876x; 1.0467x over previous
//
#include <hip/hip_runtime.h>
#include <math.h>

#define FF 256
#define CC 100000
#define PMARG 0.2f
#define NMARG 0.3f
#define NCT 6250                 // col-tiles of 16 (6250*16 == CC exactly)
#define NGB 1563                 // gemm blocks: 4 waves x 1 ct
#define NPART (NGB * 4)          // per-wave partial slots (6252)
#define RPB 12500                // repack blocks (8KB linear V each)
#define W_A 0                    // ws floats: A-pack bf16 frags (32KB)
#define W_GRAM 8192              // Gram 64x64 f32
#define W_SE 12288               // 64 row exp-sums
#define W_PART 12352             // per-wave exp partials: NPART*64 floats
#define W_VPACK_BYTES 2000000ULL // vpack bf16 fragments: 51.2MB
#define WS_NEED (W_VPACK_BYTES + (size_t)NCT * 512 * 16)

typedef __attribute__((ext_vector_type(8))) short short8;   // 8 bf16 = 4 VGPR
typedef __attribute__((ext_vector_type(4))) float f32x4;

__device__ __forceinline__ float wredf(float v) {
#pragma unroll
    for (int s = 1; s < 64; s <<= 1) v += __shfl_xor(v, s, 64);
    return v;
}
__device__ __forceinline__ short f2bf(float f) {
    unsigned u = __float_as_uint(f);
    unsigned r = (u + 0x7fffu + ((u >> 16) & 1u)) >> 16;
    return (short)r;
}
__device__ __forceinline__ short8 pack8(float4 a, float4 b) {
    short8 o;
    o[0] = f2bf(a.x); o[1] = f2bf(a.y); o[2] = f2bf(a.z); o[3] = f2bf(a.w);
    o[4] = f2bf(b.x); o[5] = f2bf(b.y); o[6] = f2bf(b.z); o[7] = f2bf(b.w);
    return o;
}
__device__ __forceinline__ short8 pack8v(f32x4 a, f32x4 b) {
    short8 o;
    o[0] = f2bf(a[0]); o[1] = f2bf(a[1]); o[2] = f2bf(a[2]); o[3] = f2bf(a[3]);
    o[4] = f2bf(b[0]); o[5] = f2bf(b[1]); o[6] = f2bf(b[2]); o[7] = f2bf(b[3]);
    return o;
}
__device__ __forceinline__ float dot4(float4 a, float4 b) {
    return a.x * b.x + a.y * b.y + a.z * b.z + a.w * b.w;
}

// Merged producer:
//  blocks 0..63  : Gram row b (64 outputs, 4-way k-split per output, f32)
//  block 64      : A-pack into bf16 MFMA fragments
//  blocks 65..   : repack V -> vpack. CONTIGUOUS 32B reads (no latency chain
//                  beyond 2 loads), SCATTERED 16B fragment writes (stores are
//                  fire-and-forget -> no chain). 12500 blocks of pure TLP.
__global__ __launch_bounds__(256) void k_produce(const float* __restrict__ in,
                                                 const float* __restrict__ V,
                                                 float* __restrict__ ws) {
    int tid = threadIdx.x;
    int b = blockIdx.x;
    const float4* __restrict__ in4 = (const float4*)in;

    if (b < 64) {
        __shared__ float sS[256];
        int r = b;
        int c = tid & 63, part = tid >> 6;
        float s = 0.f;
#pragma unroll
        for (int i = 0; i < 16; ++i) {
            int kq = part * 16 + i;
            s += dot4(in4[r * 64 + kq], in4[c * 64 + kq]);
        }
        sS[tid] = s;
        __syncthreads();
        if (tid < 64)
            ws[W_GRAM + r * 64 + tid] =
                sS[tid] + sS[64 + tid] + sS[128 + tid] + sS[192 + tid];
        return;
    }
    if (b == 64) {
        short8* __restrict__ wsa = (short8*)(ws + W_A);
#pragma unroll
        for (int i = 0; i < 8; ++i) {
            int idx = i * 256 + tid;          // (mt*8+ks)*64 + lane
            int lane = idx & 63;
            int ks = (idx >> 6) & 7;
            int mt = idx >> 9;
            int row = mt * 16 + (lane & 15);
            int kq = ks * 8 + (lane >> 4) * 2;
            wsa[idx] = pack8(in4[row * 64 + kq], in4[row * 64 + kq + 1]);
        }
        return;
    }

    // ---- repack: linear read, scattered fragment write ----
    int i = (b - 65) * 256 + tid;             // 0 .. 3199999
    int e0 = i * 8;                           // first of 8 consecutive floats
    int row = e0 >> 8;                        // V row (0..99999)
    int kk = e0 & 255;
    int ks = kk >> 5;
    int g = (kk >> 3) & 3;
    int ct = row >> 4;
    int c4 = row & 15;
    const float4* __restrict__ s = (const float4*)V + (e0 >> 2);
    float4 x = s[0];
    float4 y = s[1];
    short8* __restrict__ vp = (short8*)((char*)ws + W_VPACK_BYTES);
    vp[(size_t)ct * 512 + ks * 64 + g * 16 + c4] = pack8(x, y);
}

// GEMM from vpack (the empirically-fast consumption shape): wave = 1 distinct
// ct (16 cols x all 64 rows), 8 coalesced L3-hot 16B loads, 32 MFMA.
// No LDS, no __syncthreads; per-wave partials straight to ws.
__global__ __launch_bounds__(256, 2) void k_gemm3v(const float* __restrict__ ws_in,
                                                   float* __restrict__ logits,
                                                   float* __restrict__ ws) {
    int tid = threadIdx.x;
    int lane = tid & 63, w = tid >> 6;
    int ct = blockIdx.x * 4 + w;                // 0..6251 (tail clamped)
    int g = lane >> 4, c4 = lane & 15;
    bool ctv = ct < NCT;
    int cts = ctv ? ct : 0;

    const short8* __restrict__ vp =
        (const short8*)((const char*)ws_in + W_VPACK_BYTES) + (size_t)cts * 512 + lane;
    short8 bfr[8];
#pragma unroll
    for (int ks = 0; ks < 8; ++ks) bfr[ks] = vp[ks * 64];   // coalesced bf16

    const short8* __restrict__ ap = (const short8*)(ws_in + W_A) + lane;
    f32x4 acc[4];
#pragma unroll
    for (int mt = 0; mt < 4; ++mt) acc[mt] = (f32x4){0.f, 0.f, 0.f, 0.f};
#pragma unroll
    for (int ks = 0; ks < 8; ++ks)
#pragma unroll
        for (int mt = 0; mt < 4; ++mt) {
            short8 a = ap[(mt * 8 + ks) * 64];   // L1-hot, coalesced
            acc[mt] = __builtin_amdgcn_mfma_f32_16x16x32_bf16(a, bfr[ks],
                                                              acc[mt], 0, 0, 0);
        }

    int col = ct * 16 + c4;
    float* __restrict__ P = ws + W_PART + (size_t)(blockIdx.x * 4 + w) * 64;
#pragma unroll
    for (int mt = 0; mt < 4; ++mt)
#pragma unroll
        for (int r = 0; r < 4; ++r) {
            int row = mt * 16 + g * 4 + r;
            float lg = acc[mt][r];
            if (ctv) logits[(size_t)row * CC + col] = lg;
            float e = ctv ? expf(lg) : 0.f;      // |logit| <= ~19, safe
            e += __shfl_xor(e, 1, 64); e += __shfl_xor(e, 2, 64);
            e += __shfl_xor(e, 4, 64); e += __shfl_xor(e, 8, 64);
            if (c4 == 0) P[row] = e;             // deterministic
        }
}

// Fallback: raw-V streaming gemm, used only if ws too small for vpack
__global__ __launch_bounds__(256, 2) void k_gemm3(const float* __restrict__ V,
                                                  const float* __restrict__ ws_in,
                                                  float* __restrict__ logits,
                                                  float* __restrict__ ws) {
    int tid = threadIdx.x;
    int lane = tid & 63, w = tid >> 6;
    int ct = blockIdx.x * 4 + w;
    int g = lane >> 4, c4 = lane & 15;
    bool ctv = ct < NCT;
    int vr = ctv ? (ct * 16 + c4) : (CC - 1);
    const f32x4* __restrict__ vp = (const f32x4*)V + (size_t)vr * 64 + g * 2;
    f32x4 bv[8][2];
#pragma unroll
    for (int ks = 0; ks < 8; ++ks) {
        bv[ks][0] = vp[ks * 8];
        bv[ks][1] = vp[ks * 8 + 1];
    }
    const short8* __restrict__ ap = (const short8*)(ws_in + W_A) + lane;
    f32x4 acc[4];
#pragma unroll
    for (int mt = 0; mt < 4; ++mt) acc[mt] = (f32x4){0.f, 0.f, 0.f, 0.f};
#pragma unroll
    for (int ks = 0; ks < 8; ++ks) {
        short8 bf = pack8v(bv[ks][0], bv[ks][1]);
#pragma unroll
        for (int mt = 0; mt < 4; ++mt) {
            short8 a = ap[(mt * 8 + ks) * 64];
            acc[mt] = __builtin_amdgcn_mfma_f32_16x16x32_bf16(a, bf, acc[mt], 0, 0, 0);
        }
    }
    int col = ct * 16 + c4;
    float* __restrict__ P = ws + W_PART + (size_t)(blockIdx.x * 4 + w) * 64;
#pragma unroll
    for (int mt = 0; mt < 4; ++mt)
#pragma unroll
        for (int r = 0; r < 4; ++r) {
            int row = mt * 16 + g * 4 + r;
            float lg = acc[mt][r];
            if (ctv) logits[(size_t)row * CC + col] = lg;
            float e = ctv ? expf(lg) : 0.f;
            e += __shfl_xor(e, 1, 64); e += __shfl_xor(e, 2, 64);
            e += __shfl_xor(e, 4, 64); e += __shfl_xor(e, 8, 64);
            if (c4 == 0) P[row] = e;
        }
}

// 64 blocks (one per batch row): deterministic reduce of exp partials
__global__ __launch_bounds__(256) void k_comb(const float* __restrict__ ws_in,
                                              float* __restrict__ ws) {
    __shared__ float sS[256];
    int row = blockIdx.x;
    int tid = threadIdx.x;
    const float* __restrict__ P = ws_in + W_PART;
    float s = 0.f;
    for (int b = tid; b < NPART; b += 256) s += P[(size_t)b * 64 + row];
    sS[tid] = s;
    __syncthreads();
    if (tid < 128) sS[tid] += sS[tid + 128];
    __syncthreads();
    if (tid < 64) {
        float v = sS[tid] + sS[tid + 64];
        v = wredf(v);
        if (tid == 0) ws[W_SE + row] = v;
    }
}

__device__ __forceinline__ bool mask_at(const void* p, int idx, int mode) {
    if (mode == 0) return ((const int*)p)[idx] != 0;
    if (mode == 1) return ((const float*)p)[idx] != 0.f;
    return ((const unsigned char*)p)[idx] != 0;
}

// 1 block x 256 threads: stage G + masks into LDS, wave 0 runs the tail
__global__ __launch_bounds__(256) void k_final(const int* __restrict__ targets,
                                               const void* __restrict__ pmask,
                                               const void* __restrict__ nmask,
                                               const float* __restrict__ logits,
                                               const float* __restrict__ ws,
                                               float* __restrict__ out) {
    __shared__ float sG[4096];
    __shared__ char sPM[16384];
    __shared__ char sNM[16384];
    __shared__ int sMode;
    int tid = threadIdx.x;

    float myLogit = 0.f, mySe = 0.f;
    if (tid < 64) {
        int tgt = targets[tid];
        myLogit = logits[(size_t)tid * CC + tgt];
        mySe = ws[W_SE + tid];
    }
    {
        const float4* __restrict__ G4 = (const float4*)(ws + W_GRAM);
        float4* sG4 = (float4*)sG;
#pragma unroll
        for (int i = 0; i < 4; ++i) sG4[tid + i * 256] = G4[tid + i * 256];
    }
    if (tid < 64) {
        const unsigned int* pw = (const unsigned int*)pmask;
        int okInt = 1, okFlt = 1;
#pragma unroll
        for (int i = 0; i < 16; ++i) {
            unsigned int wv = pw[tid * 16 + i];
            okInt = okInt && (wv <= 1u);
            okFlt = okFlt && (wv == 0u || wv == 0x3f800000u);
        }
        int mode = __all(okInt) ? 0 : (__all(okFlt) ? 1 : 2);
        if (tid == 0) sMode = mode;
    }
    __syncthreads();
    int mode = sMode;
    int mq = (mode == 2) ? 256 : 1024;
    for (int i = tid; i < mq; i += 256) {
        ((float4*)sPM)[i] = ((const float4*)pmask)[i];
        ((float4*)sNM)[i] = ((const float4*)nmask)[i];
    }
    __syncthreads();
    if (tid >= 64) return;

    int lane = tid;
    float lse = logf(mySe);
    float nll = lse - myLogit;

    float rinv = rsqrtf(sG[lane * 64 + lane]);

    float minp = INFINITY, maxthd = -INFINITY;
    for (int j = 0; j < 64; ++j) {
        float rj = __shfl(rinv, j, 64);
        float sim = sG[lane * 64 + j] * rinv * rj;
        sim = fminf(1.f, fmaxf(-1.f, sim));
        if (j != lane) {
            bool pm = mask_at(sPM, lane * 64 + j, mode);
            float ps = pm ? sim : 2.0f;
            minp = fminf(minp, ps);
            maxthd = fmaxf(maxthd, pm ? sim : -2.0f);   // sentinel 2.0 -> -2.0
        }
    }
    float n_thrd = minp - NMARG;
    float p_thrd = maxthd - PMARG;

    float hps = 0.f, hns = 0.f, hpc = 0.f, hnc = 0.f;
    for (int j = 0; j < 64; ++j) {
        float rj = __shfl(rinv, j, 64);
        float sim = sG[lane * 64 + j] * rinv * rj;
        sim = fminf(1.f, fmaxf(-1.f, sim));
        if (j != lane) {
            bool pm = mask_at(sPM, lane * 64 + j, mode);
            bool nm = mask_at(sNM, lane * 64 + j, mode);
            float ps = pm ? sim : 2.0f;
            float ns = nm ? sim : 2.0f;
            if (ps < p_thrd) { hps += log1pf(expf(-ps)); hpc += 1.f; }
            if (ns < n_thrd) { hns += log1pf(expf(-ns)); hnc += 1.f; }
        }
    }

    float snll = wredf(nll);
    float shps = wredf(hps);
    float shns = wredf(hns);
    float shpc = wredf(hpc);
    float shnc = wredf(hnc);
    if (lane == 0) {
        float bu = snll * (1.f / 64.f);
        float hp = shpc > 0.f ? shps / shpc : 0.f;
        float hn = shnc > 0.f ? shns / shnc : 0.f;
        out[0] = bu + hp + hn;
    }
}

extern "C" void kernel_launch(void* const* d_in, const int* in_sizes, int n_in,
                              void* d_out, int out_size, void* d_ws, size_t ws_size,
                              hipStream_t stream) {
    const float* inputs = (const float*)d_in[0];
    const int* targets  = (const int*)d_in[1];
    const void* pmask   = d_in[2];
    const void* nmask   = d_in[3];
    const float* V      = (const float*)d_in[4];
    float* out = (float*)d_out;      // out[0] = loss
    float* logits = out + 1;         // out[1..] = logits [64][100000] row-major
    float* ws = (float*)d_ws;        // A-pack | Gram | se | partials | vpack

    if (ws_size >= WS_NEED) {
        hipLaunchKernelGGL(k_produce, dim3(65 + RPB), dim3(256), 0, stream,
                           inputs, V, ws);
        hipLaunchKernelGGL(k_gemm3v, dim3(NGB), dim3(256), 0, stream,
                           ws, logits, ws);
    } else {
        hipLaunchKernelGGL(k_produce, dim3(65), dim3(256), 0, stream,
                           inputs, V, ws);
        hipLaunchKernelGGL(k_gemm3, dim3(NGB), dim3(256), 0, stream,
                           V, ws, logits, ws);
    }
    hipLaunchKernelGGL(k_comb, dim3(64), dim3(256), 0, stream, ws, ws);
    hipLaunchKernelGGL(k_final, dim3(1), dim3(256), 0, stream,
                       targets, pmask, nmask, logits, ws, out);
}